// Round 1
// baseline (699.398 us; speedup 1.0000x reference)
//
#include <hip/hip_runtime.h>

typedef _Float16 f16;
typedef _Float16 f16x4 __attribute__((ext_vector_type(4)));
typedef _Float16 f16x8 __attribute__((ext_vector_type(8)));
typedef float f32x4 __attribute__((ext_vector_type(4)));

__device__ __forceinline__ f32x4 mfma16(f16x8 a, f16x8 b, f32x4 c) {
  return __builtin_amdgcn_mfma_f32_16x16x32_f16(a, b, c, 0, 0, 0);
}

__device__ __forceinline__ float sigmoid_(float x) { return 1.f / (1.f + __expf(-x)); }
__device__ __forceinline__ float tanh_(float x) { return 1.f - 2.f / (__expf(2.f * x) + 1.f); }

// ---------------------------------------------------------------------------
// fp32 -> fp16 conversion, 4 elements/thread
// ---------------------------------------------------------------------------
__global__ void cvt_kernel(const float* __restrict__ src, f16* __restrict__ dst, int n4) {
  int i = blockIdx.x * 256 + threadIdx.x;
  if (i < n4) {
    float4 v = ((const float4*)src)[i];
    f16x4 h = {(f16)v.x, (f16)v.y, (f16)v.z, (f16)v.w};
    ((f16x4*)dst)[i] = h;
  }
}

// ---------------------------------------------------------------------------
// GEMM1: vd[2048,512] += v[2048,20000] @ W_down^T[20000,512]
// A fp32 (converted in staging), B fp16 pre-converted. Tile 64x512, K-split 16.
// grid (16 ksplit, 32 mtile); XCD = blockIdx.x % 8 keeps B k-slab L2-resident.
// ---------------------------------------------------------------------------
__global__ __launch_bounds__(256, 2) void gemm1_kernel(
    const float* __restrict__ A, const f16* __restrict__ B, float* __restrict__ C) {
  constexpr int K = 20000, N = 512;
  __shared__ f16 Al[64][40];
  __shared__ f16 Bl[512][40];
  int tid = threadIdx.x;
  int m0 = blockIdx.y * 64;
  int split = blockIdx.x;
  int it0 = (split * 625) >> 4;
  int it1 = ((split + 1) * 625) >> 4;
  int wid = tid >> 6, lane = tid & 63;
  int lm = lane & 15, quad = lane >> 4;

  f32x4 acc[4][8];
#pragma unroll
  for (int i = 0; i < 4; ++i)
#pragma unroll
    for (int j = 0; j < 8; ++j) acc[i][j] = (f32x4){0.f, 0.f, 0.f, 0.f};

  for (int it = it0; it < it1; ++it) {
    int k0 = it * 32;
    __syncthreads();
    // stage A (fp32 -> fp16): 64 rows x 32 cols, 8 lanes/row (128B coalesced)
#pragma unroll
    for (int i = 0; i < 2; ++i) {
      int slot = tid + i * 256;
      int row = slot >> 3, seg = slot & 7;
      float4 v = *(const float4*)(A + (size_t)(m0 + row) * K + k0 + seg * 4);
      f16x4 h = {(f16)v.x, (f16)v.y, (f16)v.z, (f16)v.w};
      *(f16x4*)&Al[row][seg * 4] = h;
    }
    // stage B (fp16): 512 rows x 32 cols
#pragma unroll
    for (int i = 0; i < 8; ++i) {
      int slot = tid + i * 256;
      int row = slot >> 2, seg = slot & 3;
      *(f16x8*)&Bl[row][seg * 8] = *(const f16x8*)(B + (size_t)row * K + k0 + seg * 8);
    }
    __syncthreads();
    f16x8 af[4], bf[8];
#pragma unroll
    for (int mi = 0; mi < 4; ++mi) af[mi] = *(const f16x8*)&Al[mi * 16 + lm][quad * 8];
#pragma unroll
    for (int ni = 0; ni < 8; ++ni) bf[ni] = *(const f16x8*)&Bl[wid * 128 + ni * 16 + lm][quad * 8];
#pragma unroll
    for (int mi = 0; mi < 4; ++mi)
#pragma unroll
      for (int ni = 0; ni < 8; ++ni) acc[mi][ni] = mfma16(af[mi], bf[ni], acc[mi][ni]);
  }
  // epilogue: atomic accumulate fp32 (K-split reduction)
#pragma unroll
  for (int mi = 0; mi < 4; ++mi)
#pragma unroll
    for (int ni = 0; ni < 8; ++ni)
#pragma unroll
      for (int r = 0; r < 4; ++r) {
        int row = m0 + mi * 16 + quad * 4 + r;
        int col = wid * 128 + ni * 16 + lm;
        atomicAdd(&C[(size_t)row * N + col], acc[mi][ni][r]);
      }
}

// ---------------------------------------------------------------------------
// build vt[2048,640] f16 = [ vd | t*Wt_up_w + Wt_up_b ]
// ---------------------------------------------------------------------------
__global__ void build_vt_kernel(const float* __restrict__ vd, const float* __restrict__ t,
                                const float* __restrict__ wtw, const float* __restrict__ wtb,
                                f16* __restrict__ vt) {
  int m = blockIdx.x;
  float tv = t[m];
  for (int c = threadIdx.x; c < 640; c += 256) {
    float val = (c < 512) ? vd[(size_t)m * 512 + c] : (tv * wtw[c - 512] + wtb[c - 512]);
    vt[(size_t)m * 640 + c] = (f16)val;
  }
}

// ---------------------------------------------------------------------------
// 128x128-tile fp16 GEMM: C[M,N] = A[M,K] @ Bt[N,K]^T  (both K-contiguous)
// EPI 0: plain f16 store (row*N+col).
// EPI 1: xg layout — row m -> (l=m&15, b=m>>4), store (l*128+b)*N+col, add biases.
// ---------------------------------------------------------------------------
template <int EPI>
__global__ __launch_bounds__(256, 2) void gemm128_kernel(
    const f16* __restrict__ A, const f16* __restrict__ B, f16* __restrict__ out,
    const float* __restrict__ bias0, const float* __restrict__ bias1, int K_iters, int N) {
  __shared__ f16 Al[128][40];
  __shared__ f16 Bl[128][40];
  int tid = threadIdx.x;
  int m0 = blockIdx.y * 128, n0 = blockIdx.x * 128;
  int wid = tid >> 6, lane = tid & 63;
  int wm = wid & 1, wn = wid >> 1;
  int lm = lane & 15, quad = lane >> 4;
  int K = K_iters * 32;

  f32x4 acc[4][4];
#pragma unroll
  for (int i = 0; i < 4; ++i)
#pragma unroll
    for (int j = 0; j < 4; ++j) acc[i][j] = (f32x4){0.f, 0.f, 0.f, 0.f};

  for (int it = 0; it < K_iters; ++it) {
    int k0 = it * 32;
    __syncthreads();
#pragma unroll
    for (int i = 0; i < 2; ++i) {
      int slot = tid + i * 256;
      int row = slot >> 2, seg = slot & 3;
      *(f16x8*)&Al[row][seg * 8] = *(const f16x8*)(A + (size_t)(m0 + row) * K + k0 + seg * 8);
      *(f16x8*)&Bl[row][seg * 8] = *(const f16x8*)(B + (size_t)(n0 + row) * K + k0 + seg * 8);
    }
    __syncthreads();
    f16x8 af[4], bf[4];
#pragma unroll
    for (int mi = 0; mi < 4; ++mi) af[mi] = *(const f16x8*)&Al[wm * 64 + mi * 16 + lm][quad * 8];
#pragma unroll
    for (int ni = 0; ni < 4; ++ni) bf[ni] = *(const f16x8*)&Bl[wn * 64 + ni * 16 + lm][quad * 8];
#pragma unroll
    for (int mi = 0; mi < 4; ++mi)
#pragma unroll
      for (int ni = 0; ni < 4; ++ni) acc[mi][ni] = mfma16(af[mi], bf[ni], acc[mi][ni]);
  }
#pragma unroll
  for (int mi = 0; mi < 4; ++mi)
#pragma unroll
    for (int ni = 0; ni < 4; ++ni)
#pragma unroll
      for (int r = 0; r < 4; ++r) {
        int row = m0 + wm * 64 + mi * 16 + quad * 4 + r;
        int col = n0 + wn * 64 + ni * 16 + lm;
        float val = acc[mi][ni][r];
        if (EPI == 0) {
          out[(size_t)row * N + col] = (f16)val;
        } else {
          int l = row & 15, b = row >> 4;
          out[(size_t)(l * 128 + b) * N + col] = (f16)(val + bias0[col] + bias1[col]);
        }
      }
}

// ---------------------------------------------------------------------------
// LSTM step: gates[128,4096] = xg_l + h @ W_hh^T (+biases already in xg)
// grid (32 hid-slices, 4 b-slices); block = 32b x 32hid; wave w = gate w.
// ---------------------------------------------------------------------------
__global__ void lstm_step_kernel(const f16* __restrict__ h_in, const f16* __restrict__ Whh,
                                 const f16* __restrict__ xg_l, float* __restrict__ c,
                                 f16* __restrict__ h_out, float* __restrict__ h_f32) {
  __shared__ f16 Al[32][40];
  __shared__ f16 Bl[128][40];
  __shared__ float gl[32][132];
  int tid = threadIdx.x;
  int w = tid >> 6, lane = tid & 63;
  int lm = lane & 15, quad = lane >> 4;
  int h0 = blockIdx.x * 32, b0 = blockIdx.y * 32;

  f32x4 acc[2][2];
#pragma unroll
  for (int i = 0; i < 2; ++i)
#pragma unroll
    for (int j = 0; j < 2; ++j) acc[i][j] = (f32x4){0.f, 0.f, 0.f, 0.f};

  for (int it = 0; it < 32; ++it) {
    int k0 = it * 32;
    __syncthreads();
    if (tid < 128) {  // stage A: h rows b0..b0+31
      int row = tid >> 2, seg = tid & 3;
      *(f16x8*)&Al[row][seg * 8] = *(const f16x8*)(h_in + (size_t)(b0 + row) * 1024 + k0 + seg * 8);
    }
#pragma unroll
    for (int i = 0; i < 2; ++i) {  // stage B: 4 gate-strips of 32 W_hh rows
      int slot = tid + i * 256;
      int row = slot >> 2, seg = slot & 3;
      int wr = (row >> 5) * 1024 + h0 + (row & 31);
      *(f16x8*)&Bl[row][seg * 8] = *(const f16x8*)(Whh + (size_t)wr * 1024 + k0 + seg * 8);
    }
    __syncthreads();
    f16x8 a0 = *(const f16x8*)&Al[lm][quad * 8];
    f16x8 a1 = *(const f16x8*)&Al[16 + lm][quad * 8];
    f16x8 bb0 = *(const f16x8*)&Bl[w * 32 + lm][quad * 8];
    f16x8 bb1 = *(const f16x8*)&Bl[w * 32 + 16 + lm][quad * 8];
    acc[0][0] = mfma16(a0, bb0, acc[0][0]);
    acc[0][1] = mfma16(a0, bb1, acc[0][1]);
    acc[1][0] = mfma16(a1, bb0, acc[1][0]);
    acc[1][1] = mfma16(a1, bb1, acc[1][1]);
  }
  __syncthreads();
#pragma unroll
  for (int mi = 0; mi < 2; ++mi)
#pragma unroll
    for (int ni = 0; ni < 2; ++ni)
#pragma unroll
      for (int r = 0; r < 4; ++r)
        gl[mi * 16 + quad * 4 + r][w * 32 + ni * 16 + lm] = acc[mi][ni][r];
  __syncthreads();
#pragma unroll
  for (int i = 0; i < 4; ++i) {
    int idx = tid + i * 256;
    int bl = idx >> 5, hl = idx & 31;
    int gb = b0 + bl, gh = h0 + hl;
    const f16* xr = xg_l + (size_t)gb * 4096;
    float xi = (float)xr[gh] + gl[bl][hl];
    float xf = (float)xr[1024 + gh] + gl[bl][32 + hl];
    float xg = (float)xr[2048 + gh] + gl[bl][64 + hl];
    float xo = (float)xr[3072 + gh] + gl[bl][96 + hl];
    float iv = sigmoid_(xi), fv = sigmoid_(xf), gv = tanh_(xg), ov = sigmoid_(xo);
    size_t ci = (size_t)gb * 1024 + gh;
    float cc = fv * c[ci] + iv * gv;
    c[ci] = cc;
    float hh = ov * tanh_(cc);
    h_out[ci] = (f16)hh;
    h_f32[ci] = hh;
  }
}

// ---------------------------------------------------------------------------
// pred[b] = dot(h[b], lin_w) + lin_b
// ---------------------------------------------------------------------------
__global__ void pred_kernel(const float* __restrict__ h, const float* __restrict__ w,
                            const float* __restrict__ b, float* __restrict__ out) {
  int bb = blockIdx.x, tid = threadIdx.x;
  float4 hv = *(const float4*)(h + (size_t)bb * 1024 + tid * 4);
  float4 wv = *(const float4*)(w + tid * 4);
  float s = hv.x * wv.x + hv.y * wv.y + hv.z * wv.z + hv.w * wv.w;
#pragma unroll
  for (int off = 32; off > 0; off >>= 1) s += __shfl_down(s, off);
  __shared__ float red[4];
  if ((tid & 63) == 0) red[tid >> 6] = s;
  __syncthreads();
  if (tid == 0) out[bb] = red[0] + red[1] + red[2] + red[3] + b[0];
}

// ---------------------------------------------------------------------------
extern "C" void kernel_launch(void* const* d_in, const int* in_sizes, int n_in,
                              void* d_out, int out_size, void* d_ws, size_t ws_size,
                              hipStream_t stream) {
  (void)in_sizes; (void)n_in; (void)out_size; (void)ws_size;
  const float* v      = (const float*)d_in[0];
  const float* t      = (const float*)d_in[1];
  const float* W_down = (const float*)d_in[2];
  const float* Wt_w   = (const float*)d_in[3];
  const float* Wt_b   = (const float*)d_in[4];
  const float* W_vt   = (const float*)d_in[5];
  const float* W_ih   = (const float*)d_in[6];
  const float* W_hh   = (const float*)d_in[7];
  const float* b_ih   = (const float*)d_in[8];
  const float* b_hh   = (const float*)d_in[9];
  const float* lin_w  = (const float*)d_in[10];
  const float* lin_b  = (const float*)d_in[11];

  char* ws = (char*)d_ws;
  constexpr size_t OFF_WDOWN = 0;         // 20,480,000 B : W_down f16 [512][20000]
  constexpr size_t OFF_WVT   = 20480000;  //    655,360 B : W_vt  f16 [512][640]
  constexpr size_t OFF_WIH   = 21135360;  //  4,194,304 B : W_ih  f16 [4096][512]
  constexpr size_t OFF_WHH   = 25329664;  //  8,388,608 B : W_hh  f16 [4096][1024]
  constexpr size_t OFF_VD    = 33718272;  //  4,194,304 B : vd    f32 [2048][512]
  constexpr size_t OFF_VT    = 37912576;  //  2,621,440 B : vt    f16 [2048][640]
  constexpr size_t OFF_IN    = 40534016;  //  2,097,152 B : inputs f16 [2048][512]
  constexpr size_t OFF_XG    = 42631168;  // 16,777,216 B : xg    f16 [16][128][4096]
  constexpr size_t OFF_H0    = 59408384;  //    262,144 B : h ping f16
  constexpr size_t OFF_C     = 59670528;  //    524,288 B : c f32 (contiguous w/ H0 for memset)
  constexpr size_t OFF_H1    = 60194816;  //    262,144 B : h pong f16
  constexpr size_t OFF_HF    = 60456960;  //    524,288 B : h f32 (final)

  f16* wdown16 = (f16*)(ws + OFF_WDOWN);
  f16* wvt16   = (f16*)(ws + OFF_WVT);
  f16* wih16   = (f16*)(ws + OFF_WIH);
  f16* whh16   = (f16*)(ws + OFF_WHH);
  float* vd    = (float*)(ws + OFF_VD);
  f16* vt16    = (f16*)(ws + OFF_VT);
  f16* in16    = (f16*)(ws + OFF_IN);
  f16* xg16    = (f16*)(ws + OFF_XG);
  float* cbuf  = (float*)(ws + OFF_C);
  float* hf32  = (float*)(ws + OFF_HF);
  f16* hb[2]   = {(f16*)(ws + OFF_H0), (f16*)(ws + OFF_H1)};

  hipMemsetAsync(ws + OFF_VD, 0, 4194304, stream);   // vd accumulator
  hipMemsetAsync(ws + OFF_H0, 0, 786432, stream);    // h0 + c

  cvt_kernel<<<10000, 256, 0, stream>>>(W_down, wdown16, 2560000);
  cvt_kernel<<<320, 256, 0, stream>>>(W_vt, wvt16, 81920);
  cvt_kernel<<<2048, 256, 0, stream>>>(W_ih, wih16, 524288);
  cvt_kernel<<<4096, 256, 0, stream>>>(W_hh, whh16, 1048576);

  gemm1_kernel<<<dim3(16, 32), 256, 0, stream>>>(v, wdown16, vd);
  build_vt_kernel<<<2048, 256, 0, stream>>>(vd, t, Wt_w, Wt_b, vt16);
  gemm128_kernel<0><<<dim3(4, 16), 256, 0, stream>>>(vt16, wvt16, in16, nullptr, nullptr, 20, 512);
  gemm128_kernel<1><<<dim3(32, 16), 256, 0, stream>>>(in16, wih16, xg16, b_ih, b_hh, 16, 4096);

  for (int l = 0; l < 16; ++l) {
    lstm_step_kernel<<<dim3(32, 4), 256, 0, stream>>>(
        hb[l & 1], whh16, xg16 + (size_t)l * 128 * 4096, cbuf, hb[(l + 1) & 1], hf32);
  }
  pred_kernel<<<128, 256, 0, stream>>>(hf32, lin_w, lin_b, (float*)d_out);
}